// Round 1
// baseline (215.851 us; speedup 1.0000x reference)
//
#include <hip/hip_runtime.h>
#include <hip/hip_bf16.h>

// ---------------------------------------------------------------------------
// TransformerPlanner: algebra-collapsed fused implementation.
// tokens = LN(x*u + y*w + base_t) is affine in (x,y) given rs_t, which is a
// closed-form quadratic in (x,y). k-projection + QK^T collapse into per-score
// 3-FMA form; softmax->V->out_proj collapse into one GEMM vs precomputed
// OM (128x192). Remaining per-element GEMMs (attn-combined, fc1, fc2) are
// batched 16 elements/WG (M=48) and run on bf16 MFMA 16x16x32.
//
// R1 changes vs 215us baseline:
//  - LDS 63744 -> 50688 B via liveness-based aliasing (h1 aliases S1, X
//    aliases Z) => 3 WGs/CU instead of 2 (+50% occupancy).
//  - P4/P7 LayerNorm phases: 4 threads/row (192 threads, 3 full waves)
//    with register-resident row quarters + __shfl_xor reductions, instead
//    of 48 threads on a single wave walking 128 dims serially.
//  - __launch_bounds__(256,3) to hold VGPRs under the 3-wave/EU cap.
// ---------------------------------------------------------------------------

typedef __bf16 bf16x8 __attribute__((ext_vector_type(8)));
typedef float  f32x4  __attribute__((ext_vector_type(4)));
static_assert(sizeof(bf16x8) == 16, "bf16x8 must be 16B");

__device__ __forceinline__ unsigned short f2b(float x) {
  __bf16 h = (__bf16)x;
  return __builtin_bit_cast(unsigned short, h);
}
__device__ __forceinline__ float b2f(unsigned short u) {
  return (float)__builtin_bit_cast(__bf16, u);
}
__device__ __forceinline__ float dot4(float4 a, float4 b) {
  return a.x*b.x + a.y*b.y + a.z*b.z + a.w*b.w;
}
__device__ __forceinline__ f32x4 mfma16(bf16x8 a, bf16x8 b, f32x4 c) {
  return __builtin_amdgcn_mfma_f32_16x16x32_bf16(a, b, c, 0, 0, 0);
}

// ---- workspace layout (byte offsets into d_ws) ----
#define WS_OM    0          // ushort[128*192]  combined attn GEMM weights (row n, K=192)
#define WS_FC1   49152      // ushort[256*128]  fc1 bf16 row-major (N,K)
#define WS_FC2   114688     // ushort[128*256]  fc2 bf16 row-major (N,K)
#define WS_VB    180224     // float[20*128]
#define WS_VU    190464     // float[128]
#define WS_VW    190976     // float[128]
#define WS_VC    191488     // float[128]
#define WS_QN    192000     // float[3*128]  LN'd queries
#define WS_SB    193536     // float[480]    Sb[w][h][t]
#define WS_SU    195456     // float[72]     Su[24],Sw[24],Sc[24]
#define WS_SCAL  195744     // float[3]      Suu,Sww,Suw
#define WS_SUB   195756     // float[20]
#define WS_SWB   195836     // float[20]
#define WS_SBB   195916     // float[20]

// ---------------------------------------------------------------------------
__device__ float mean128(float v, volatile float* red) {
  #pragma unroll
  for (int o = 32; o; o >>= 1) v += __shfl_down(v, o, 64);
  __syncthreads();
  if ((threadIdx.x & 63) == 0) red[threadIdx.x >> 6] = v;
  __syncthreads();
  return (red[0] + red[1]) * (1.0f / 128.0f);
}

__global__ void k_tables(
    const float* __restrict__ coord_w, const float* __restrict__ coord_b,
    const float* __restrict__ pos_emb, const float* __restrict__ side_emb,
    const float* __restrict__ query_emb,
    const float* __restrict__ tln_g, const float* __restrict__ tln_b,
    const float* __restrict__ qln_g, const float* __restrict__ qln_b,
    const float* __restrict__ ipw, const float* __restrict__ ipb,
    char* __restrict__ ws)
{
  __shared__ float red[2];
  __shared__ float qn[3][128];
  __shared__ float qmat[3][128];
  __shared__ float vecA[128];
  __shared__ float vecB[128];
  __shared__ float vecC[128];
  __shared__ float kuA[128];
  __shared__ float kwA[128];
  __shared__ float kcA[128];
  const int d = threadIdx.x;      // 128 threads
  const int t = blockIdx.x;       // 0..19 = token blocks, 20 = misc

  float u  = coord_w[d*2+0];
  float w2 = coord_w[d*2+1];
  float g  = tln_g[d];
  float mu = mean128(u,  red);
  float mw = mean128(w2, red);
  float uh = u - mu, wh = w2 - mw;

  // LN(query_emb)
  #pragma unroll
  for (int w = 0; w < 3; w++) {
    float qe = query_emb[w*128 + d];
    float m  = mean128(qe, red);
    float m2 = mean128(qe*qe, red);
    float var = m2 - m*m;
    qn[w][d] = (qe - m) * rsqrtf(var + 1e-5f) * qln_g[d] + qln_b[d];
  }
  __syncthreads();
  // q = qn @ wq^T + bq   (wq = ipw rows [0,128))
  {
    const float* wqr = ipw + d*128;
    float a0 = 0, a1 = 0, a2 = 0;
    for (int k4 = 0; k4 < 32; k4++) {
      float4 wv4 = *(const float4*)&wqr[k4*4];
      a0 += dot4(wv4, *(const float4*)&qn[0][k4*4]);
      a1 += dot4(wv4, *(const float4*)&qn[1][k4*4]);
      a2 += dot4(wv4, *(const float4*)&qn[2][k4*4]);
    }
    float bq = ipb[d];
    qmat[0][d] = a0 + bq; qmat[1][d] = a1 + bq; qmat[2][d] = a2 + bq;
  }
  __syncthreads();

  if (t < 20) {
    float base = coord_b[d] + pos_emb[(t % 10)*128 + d] + side_emb[(t < 10 ? 0 : 1)*128 + d];
    float mb = mean128(base, red);
    float bh = base - mb;
    float sub = mean128(uh*bh, red);
    float swb = mean128(wh*bh, red);
    float sbb = mean128(bh*bh, red);
    if (d == 0) {
      ((float*)(ws + WS_SUB))[t] = sub;
      ((float*)(ws + WS_SWB))[t] = swb;
      ((float*)(ws + WS_SBB))[t] = sbb;
    }
    vecA[d] = bh * g;
    __syncthreads();
    const float* wkr = ipw + (128 + d)*128;
    const float* wvr = ipw + (256 + d)*128;
    float kb = 0, vb = 0;
    for (int k4 = 0; k4 < 32; k4++) {
      float4 a4 = *(const float4*)&vecA[k4*4];
      kb += dot4(*(const float4*)&wkr[k4*4], a4);
      vb += dot4(*(const float4*)&wvr[k4*4], a4);
    }
    kuA[d] = kb;
    ((float*)(ws + WS_VB))[t*128 + d] = vb;
    __syncthreads();
    if (d < 24) {
      int w = d / 8, h = d % 8;
      float s = 0;
      #pragma unroll
      for (int dl = 0; dl < 16; dl++) s += qmat[w][h*16 + dl] * kuA[h*16 + dl];
      ((float*)(ws + WS_SB))[(w*8 + h)*20 + t] = 0.25f * s;
    }
  } else {
    float suu = mean128(uh*uh, red);
    float sww = mean128(wh*wh, red);
    float suw = mean128(uh*wh, red);
    if (d == 0) {
      float* sc = (float*)(ws + WS_SCAL);
      sc[0] = suu; sc[1] = sww; sc[2] = suw;
    }
    vecA[d] = uh * g; vecB[d] = wh * g; vecC[d] = tln_b[d];
    __syncthreads();
    const float* wkr = ipw + (128 + d)*128;
    const float* wvr = ipw + (256 + d)*128;
    float ku = 0, kw = 0, kc = 0, vu = 0, vw = 0, vc = 0;
    for (int k4 = 0; k4 < 32; k4++) {
      float4 a4 = *(const float4*)&vecA[k4*4];
      float4 b4 = *(const float4*)&vecB[k4*4];
      float4 c4 = *(const float4*)&vecC[k4*4];
      float4 kv = *(const float4*)&wkr[k4*4];
      float4 vv = *(const float4*)&wvr[k4*4];
      ku += dot4(kv, a4); kw += dot4(kv, b4); kc += dot4(kv, c4);
      vu += dot4(vv, a4); vw += dot4(vv, b4); vc += dot4(vv, c4);
    }
    kc += ipb[128 + d]; vc += ipb[256 + d];
    ((float*)(ws + WS_VU))[d] = vu;
    ((float*)(ws + WS_VW))[d] = vw;
    ((float*)(ws + WS_VC))[d] = vc;
    kuA[d] = ku; kwA[d] = kw; kcA[d] = kc;
    float* qnw = (float*)(ws + WS_QN);
    qnw[0*128 + d] = qn[0][d]; qnw[1*128 + d] = qn[1][d]; qnw[2*128 + d] = qn[2][d];
    __syncthreads();
    if (d < 24) {
      int w = d / 8, h = d % 8;
      float su = 0, sw = 0, sc2 = 0;
      #pragma unroll
      for (int dl = 0; dl < 16; dl++) {
        float q = qmat[w][h*16 + dl];
        su  += q * kuA[h*16 + dl];
        sw  += q * kwA[h*16 + dl];
        sc2 += q * kcA[h*16 + dl];
      }
      float* o = (float*)(ws + WS_SU);
      o[ 0 + w*8 + h] = 0.25f * su;
      o[24 + w*8 + h] = 0.25f * sw;
      o[48 + w*8 + h] = 0.25f * sc2;
    }
  }
}

// Build OM (128x192) and bf16 repack of fc1/fc2.
__global__ void k_build(
    const float* __restrict__ opw, const float* __restrict__ opb,
    const float* __restrict__ f1w, const float* __restrict__ f2w,
    char* __restrict__ ws)
{
  const int b = blockIdx.x, tid = threadIdx.x;
  if (b < 128) {
    __shared__ float Or[128];
    if (tid < 128) Or[tid] = opw[b*128 + tid];
    __syncthreads();
    if (tid < 192) {
      const float* VB = (const float*)(ws + WS_VB);
      const float* VU = (const float*)(ws + WS_VU);
      const float* VW = (const float*)(ws + WS_VW);
      const float* VC = (const float*)(ws + WS_VC);
      float val = 0.0f;
      if (tid < 160) {
        int h = tid / 20, tt = tid % 20;
        #pragma unroll
        for (int dl = 0; dl < 16; dl++) val += Or[h*16 + dl] * VB[tt*128 + h*16 + dl];
      } else if (tid < 168) {
        int h = tid - 160;
        #pragma unroll
        for (int dl = 0; dl < 16; dl++) val += Or[h*16 + dl] * VU[h*16 + dl];
      } else if (tid < 176) {
        int h = tid - 168;
        #pragma unroll
        for (int dl = 0; dl < 16; dl++) val += Or[h*16 + dl] * VW[h*16 + dl];
      } else if (tid == 176) {
        for (int d = 0; d < 128; d++) val += Or[d] * VC[d];
        val += opb[b];
      } else {
        val = 0.0f;
      }
      ((unsigned short*)(ws + WS_OM))[b*192 + tid] = f2b(val);
    }
  } else if (b < 144) {
    unsigned short* dst = (unsigned short*)(ws + WS_FC1);
    int i0 = (b - 128)*2048;
    #pragma unroll
    for (int j = 0; j < 8; j++) { int i = i0 + j*256 + tid; dst[i] = f2b(f1w[i]); }
  } else {
    unsigned short* dst = (unsigned short*)(ws + WS_FC2);
    int i0 = (b - 144)*2048;
    #pragma unroll
    for (int j = 0; j < 8; j++) { int i = i0 + j*256 + tid; dst[i] = f2b(f2w[i]); }
  }
}

// ---------------------------------------------------------------------------
// Main fused kernel: 16 batch elements per WG (M = 48 rows), 256 threads.
// LDS 50688 B -> 3 WGs/CU.
//
// LDS liveness / aliasing map (phase: live buffers):
//   P0-P2 : C{Z,xr,yr,rsA,Sbl,Sul,Swl,Scl}           (25344 B)
//   P3    : C{Z} (read) + S1 (write)                 (peak: 50688 B)
//   P4    : S1 (read) + X (write; aliases Z, dead)
//   P5    : X (read) + h1 (write; aliases S1, dead)
//   P6    : h1 (read) -> barrier -> S1/h2 (write, same region)
//   P7    : S1 (read) + X (read)
#define GE 16
#define MR 48

__global__ __launch_bounds__(256, 3) void k_main(
    const float* __restrict__ tl, const float* __restrict__ tr,
    const float* __restrict__ f1b, const float* __restrict__ f2b_,
    const float* __restrict__ pag, const float* __restrict__ pab,
    const float* __restrict__ pfg, const float* __restrict__ pfb,
    const float* __restrict__ hw, const float* __restrict__ hb,
    const char* __restrict__ ws, float* __restrict__ out)
{
  __shared__ __align__(16) char smem[50688];
  float* S1 = (float*)smem;                     // 48 x 132 f32 scratch (attn_out / h2)
  unsigned short* h1 = (unsigned short*)smem;   // 48 x 264 bf16, ALIASES S1 (S1 dead in P5/P6)
  char*  C  = smem + 25344;
  unsigned short* Z   = (unsigned short*)C;     // 48 x 200 bf16 (K=192 used)
  float* xr  = (float*)(C + 19200);             // 16 x 20 : x*rs (raw x before P1)
  float* yr  = (float*)(C + 20480);
  float* rsA = (float*)(C + 21760);
  float* Sbl = (float*)(C + 23040);             // 480
  float* Sul = (float*)(C + 24960);             // 24
  float* Swl = (float*)(C + 25056);             // 24
  float* Scl = (float*)(C + 25152);             // 24
  unsigned short* X  = (unsigned short*)C;      // 48 x 136 bf16 (LN1 out), ALIASES Z (dead after P3)

  const unsigned short* OM = (const unsigned short*)(ws + WS_OM);
  const unsigned short* W1 = (const unsigned short*)(ws + WS_FC1);
  const unsigned short* W2 = (const unsigned short*)(ws + WS_FC2);
  const float* QN   = (const float*)(ws + WS_QN);
  const float* SBw  = (const float*)(ws + WS_SB);
  const float* SUw  = (const float*)(ws + WS_SU);
  const float* SCAL = (const float*)(ws + WS_SCAL);
  const float* SUB  = (const float*)(ws + WS_SUB);
  const float* SWB  = (const float*)(ws + WS_SWB);
  const float* SBB  = (const float*)(ws + WS_SBB);

  const int tid  = threadIdx.x;
  const int wg   = blockIdx.x;
  const int lane = tid & 63;
  const int wv   = tid >> 6;

  // ---- P0: stage tables, init Z constant tail, load coords ----
  for (int i = tid; i < 480; i += 256) Sbl[i] = SBw[i];
  if (tid < 72) Sul[tid] = SUw[tid];   // Sul/Swl/Scl contiguous
  if (tid < 48) {
    unsigned short* Zr = Z + tid*200;
    Zr[176] = 0x3F80;                  // bf16 1.0
    #pragma unroll
    for (int i = 177; i < 192; i++) Zr[i] = 0;
  }
  if (tid < 160) {
    int half = tid / 80;               // 0 = left, 1 = right
    int i4   = tid % 80;
    const float* src = half ? tr : tl;
    float4 v = *(const float4*)(src + wg*(GE*20) + i4*4);
    int e  = i4 / 5;
    int j  = (i4 % 5) * 4;
    int t0 = half*10 + j/2;
    xr[e*20 + t0]     = v.x; yr[e*20 + t0]     = v.y;
    xr[e*20 + t0 + 1] = v.z; yr[e*20 + t0 + 1] = v.w;
  }
  __syncthreads();

  // ---- P1: rs_t = rsqrt(quadratic(x,y) + eps); xr,yr <- x*rs, y*rs ----
  {
    float suu = SCAL[0], sww = SCAL[1], suw = SCAL[2];
    for (int i = tid; i < GE*20; i += 256) {
      int t = i % 20;
      float x = xr[i], y = yr[i];
      float var = suu*x*x + sww*y*y + 2.0f*suw*x*y
                + 2.0f*SUB[t]*x + 2.0f*SWB[t]*y + SBB[t];
      float rv = rsqrtf(var + 1e-5f);
      rsA[i] = rv; xr[i] = x*rv; yr[i] = y*rv;
    }
  }
  __syncthreads();

  // ---- P2: scores + softmax + P,Q -> Z rows (bf16) ----
  if (tid < 128) {
    int e = tid >> 3, h = tid & 7;
    float xa[20], ya[20], ra[20];
    #pragma unroll
    for (int tb = 0; tb < 5; tb++) {
      float4 xv = *(const float4*)&xr[e*20 + tb*4];
      float4 yv = *(const float4*)&yr[e*20 + tb*4];
      float4 rv = *(const float4*)&rsA[e*20 + tb*4];
      xa[tb*4+0]=xv.x; xa[tb*4+1]=xv.y; xa[tb*4+2]=xv.z; xa[tb*4+3]=xv.w;
      ya[tb*4+0]=yv.x; ya[tb*4+1]=yv.y; ya[tb*4+2]=yv.z; ya[tb*4+3]=yv.w;
      ra[tb*4+0]=rv.x; ra[tb*4+1]=rv.y; ra[tb*4+2]=rv.z; ra[tb*4+3]=rv.w;
    }
    float s[3][20];
    #pragma unroll
    for (int w = 0; w < 3; w++) {
      float suv = Sul[w*8 + h], swv = Swl[w*8 + h], scv = Scl[w*8 + h];
      const float* sb = &Sbl[(w*8 + h)*20];
      #pragma unroll
      for (int tb = 0; tb < 5; tb++) {
        float4 s4 = *(const float4*)&sb[tb*4];
        s[w][tb*4+0] = fmaf(xa[tb*4+0],suv, fmaf(ya[tb*4+0],swv, fmaf(ra[tb*4+0],s4.x, scv)));
        s[w][tb*4+1] = fmaf(xa[tb*4+1],suv, fmaf(ya[tb*4+1],swv, fmaf(ra[tb*4+1],s4.y, scv)));
        s[w][tb*4+2] = fmaf(xa[tb*4+2],suv, fmaf(ya[tb*4+2],swv, fmaf(ra[tb*4+2],s4.z, scv)));
        s[w][tb*4+3] = fmaf(xa[tb*4+3],suv, fmaf(ya[tb*4+3],swv, fmaf(ra[tb*4+3],s4.w, scv)));
      }
    }
    unsigned short* Zr0 = Z + e*3*200;
    #pragma unroll
    for (int w = 0; w < 3; w++) {
      float m = s[w][0];
      #pragma unroll
      for (int t2 = 1; t2 < 20; t2++) m = fmaxf(m, s[w][t2]);
      float sum = 0;
      #pragma unroll
      for (int t2 = 0; t2 < 20; t2++) { float p = __expf(s[w][t2] - m); s[w][t2] = p; sum += p; }
      float inv = 1.0f / sum;
      float P = 0, Q = 0;
      #pragma unroll
      for (int t2 = 0; t2 < 20; t2++) { P = fmaf(s[w][t2], xa[t2], P); Q = fmaf(s[w][t2], ya[t2], Q); }
      P *= inv; Q *= inv;
      unsigned short* Zr = Zr0 + w*200;
      #pragma unroll
      for (int t2 = 0; t2 < 10; t2++) {
        unsigned int lo = f2b(s[w][2*t2]   * ra[2*t2]   * inv);
        unsigned int hi = f2b(s[w][2*t2+1] * ra[2*t2+1] * inv);
        *(unsigned int*)&Zr[h*20 + 2*t2] = lo | (hi << 16);
      }
      Zr[160 + h] = f2b(P);
      Zr[168 + h] = f2b(Q);
    }
  }
  __syncthreads();

  // ---- P3: GEMM1  attn_out(48x128) = Z(48x192) @ OM^T ----
  {
    int nbase = wv * 32;
    bf16x8 Bf[2][6];
    #pragma unroll
    for (int nt = 0; nt < 2; nt++)
      #pragma unroll
      for (int kt = 0; kt < 6; kt++) {
        int n = nbase + nt*16 + (lane & 15);
        int k = kt*32 + (lane >> 4)*8;
        Bf[nt][kt] = *(const bf16x8*)(OM + n*192 + k);
      }
    f32x4 acc[3][2];
    #pragma unroll
    for (int mt = 0; mt < 3; mt++)
      #pragma unroll
      for (int nt = 0; nt < 2; nt++) acc[mt][nt] = (f32x4){0.f,0.f,0.f,0.f};
    #pragma unroll
    for (int kt = 0; kt < 6; kt++) {
      bf16x8 Af[3];
      #pragma unroll
      for (int mt = 0; mt < 3; mt++) {
        int row = mt*16 + (lane & 15);
        int k   = kt*32 + (lane >> 4)*8;
        Af[mt] = *(const bf16x8*)(Z + row*200 + k);
      }
      #pragma unroll
      for (int mt = 0; mt < 3; mt++)
        #pragma unroll
        for (int nt = 0; nt < 2; nt++)
          acc[mt][nt] = mfma16(Af[mt], Bf[nt][kt], acc[mt][nt]);
    }
    #pragma unroll
    for (int mt = 0; mt < 3; mt++)
      #pragma unroll
      for (int nt = 0; nt < 2; nt++) {
        int col = nbase + nt*16 + (lane & 15);
        int r0  = mt*16 + ((lane >> 4) << 2);
        #pragma unroll
        for (int j = 0; j < 4; j++) S1[(r0 + j)*132 + col] = acc[mt][nt][j];
      }
  }
  __syncthreads();

  // ---- P4: x = LN(queries_n + attn_out) -> X bf16 ----
  // 4 threads per row (192 threads = 3 full waves); row quarter lives in regs.
  if (tid < 4*MR) {
    const int r = tid >> 2, q = tid & 3, w = r % 3;
    const float* s1r  = &S1[r*132 + q*32];
    const float* qrow = QN + w*128 + q*32;
    float4 va[8];
    float s1 = 0.f, s2 = 0.f;
    #pragma unroll
    for (int d4 = 0; d4 < 8; d4++) {
      float4 v  = *(const float4*)&s1r[d4*4];
      float4 q4 = *(const float4*)&qrow[d4*4];
      v.x += q4.x; v.y += q4.y; v.z += q4.z; v.w += q4.w;
      va[d4] = v;
      s1 += v.x + v.y + v.z + v.w;
      s2 += v.x*v.x + v.y*v.y + v.z*v.z + v.w*v.w;
    }
    s1 += __shfl_xor(s1, 1); s1 += __shfl_xor(s1, 2);
    s2 += __shfl_xor(s2, 1); s2 += __shfl_xor(s2, 2);
    float m  = s1 * (1.0f/128.0f);
    float sc = rsqrtf(s2 * (1.0f/128.0f) - m*m + 1e-5f);
    #pragma unroll
    for (int d4 = 0; d4 < 8; d4++) {
      int d = q*32 + d4*4;
      float4 g4 = *(const float4*)&pag[d];
      float4 b4 = *(const float4*)&pab[d];
      float a0 = (va[d4].x - m)*sc*g4.x + b4.x;
      float a1 = (va[d4].y - m)*sc*g4.y + b4.y;
      float a2 = (va[d4].z - m)*sc*g4.z + b4.z;
      float a3 = (va[d4].w - m)*sc*g4.w + b4.w;
      uint2 pk;
      pk.x = (unsigned)f2b(a0) | ((unsigned)f2b(a1) << 16);
      pk.y = (unsigned)f2b(a2) | ((unsigned)f2b(a3) << 16);
      *(uint2*)&X[r*136 + d] = pk;
    }
  }
  __syncthreads();

  // ---- P5: fc1 + relu -> h1 bf16 (48x256)  [h1 aliases S1; S1 is dead] ----
  {
    int nbase = wv * 64;
    bf16x8 Bf[4][4];
    #pragma unroll
    for (int nt = 0; nt < 4; nt++)
      #pragma unroll
      for (int kt = 0; kt < 4; kt++) {
        int n = nbase + nt*16 + (lane & 15);
        int k = kt*32 + (lane >> 4)*8;
        Bf[nt][kt] = *(const bf16x8*)(W1 + n*128 + k);
      }
    f32x4 acc[3][4];
    #pragma unroll
    for (int mt = 0; mt < 3; mt++)
      #pragma unroll
      for (int nt = 0; nt < 4; nt++) acc[mt][nt] = (f32x4){0.f,0.f,0.f,0.f};
    #pragma unroll
    for (int kt = 0; kt < 4; kt++) {
      bf16x8 Af[3];
      #pragma unroll
      for (int mt = 0; mt < 3; mt++) {
        int row = mt*16 + (lane & 15);
        int k   = kt*32 + (lane >> 4)*8;
        Af[mt] = *(const bf16x8*)(X + row*136 + k);
      }
      #pragma unroll
      for (int mt = 0; mt < 3; mt++)
        #pragma unroll
        for (int nt = 0; nt < 4; nt++)
          acc[mt][nt] = mfma16(Af[mt], Bf[nt][kt], acc[mt][nt]);
    }
    #pragma unroll
    for (int nt = 0; nt < 4; nt++) {
      int col = nbase + nt*16 + (lane & 15);
      float bb = f1b[col];
      #pragma unroll
      for (int mt = 0; mt < 3; mt++) {
        int r0 = mt*16 + ((lane >> 4) << 2);
        #pragma unroll
        for (int j = 0; j < 4; j++) {
          float v = fmaxf(acc[mt][nt][j] + bb, 0.0f);
          h1[(r0 + j)*264 + col] = f2b(v);
        }
      }
    }
  }
  __syncthreads();

  // ---- P6: h2 = fc2 @ h1 + b -> S1 f32  [S1 aliases h1: barrier before store] ----
  {
    int nbase = wv * 32;
    bf16x8 Bf[2][8];
    #pragma unroll
    for (int nt = 0; nt < 2; nt++)
      #pragma unroll
      for (int kt = 0; kt < 8; kt++) {
        int n = nbase + nt*16 + (lane & 15);
        int k = kt*32 + (lane >> 4)*8;
        Bf[nt][kt] = *(const bf16x8*)(W2 + n*256 + k);
      }
    f32x4 acc[3][2];
    #pragma unroll
    for (int mt = 0; mt < 3; mt++)
      #pragma unroll
      for (int nt = 0; nt < 2; nt++) acc[mt][nt] = (f32x4){0.f,0.f,0.f,0.f};
    #pragma unroll
    for (int kt = 0; kt < 8; kt++) {
      bf16x8 Af[3];
      #pragma unroll
      for (int mt = 0; mt < 3; mt++) {
        int row = mt*16 + (lane & 15);
        int k   = kt*32 + (lane >> 4)*8;
        Af[mt] = *(const bf16x8*)(h1 + row*264 + k);
      }
      #pragma unroll
      for (int mt = 0; mt < 3; mt++)
        #pragma unroll
        for (int nt = 0; nt < 2; nt++)
          acc[mt][nt] = mfma16(Af[mt], Bf[nt][kt], acc[mt][nt]);
    }
    __syncthreads();   // all h1 reads complete before aliased S1 stores
    #pragma unroll
    for (int nt = 0; nt < 2; nt++) {
      int col = nbase + nt*16 + (lane & 15);
      float bb = f2b_[col];
      #pragma unroll
      for (int mt = 0; mt < 3; mt++) {
        int r0 = mt*16 + ((lane >> 4) << 2);
        #pragma unroll
        for (int j = 0; j < 4; j++) S1[(r0 + j)*132 + col] = acc[mt][nt][j] + bb;
      }
    }
  }
  __syncthreads();

  // ---- P7: x2 = LN(x + h2); out = x2 @ head^T + hb ----
  // 4 threads per row; partial head dot-products reduced via shfl_xor.
  if (tid < 4*MR) {
    const int r = tid >> 2, q = tid & 3, e = r / 3, w = r % 3;
    const float* s1r = &S1[r*132 + q*32];
    float4 xv[8];
    float s1 = 0.f, s2 = 0.f;
    #pragma unroll
    for (int d4 = 0; d4 < 8; d4++) {
      float4 v = *(const float4*)&s1r[d4*4];
      uint2 u = *(const uint2*)&X[r*136 + q*32 + d4*4];
      v.x += b2f((unsigned short)(u.x & 0xffff));
      v.y += b2f((unsigned short)(u.x >> 16));
      v.z += b2f((unsigned short)(u.y & 0xffff));
      v.w += b2f((unsigned short)(u.y >> 16));
      xv[d4] = v;
      s1 += v.x + v.y + v.z + v.w;
      s2 += v.x*v.x + v.y*v.y + v.z*v.z + v.w*v.w;
    }
    s1 += __shfl_xor(s1, 1); s1 += __shfl_xor(s1, 2);
    s2 += __shfl_xor(s2, 1); s2 += __shfl_xor(s2, 2);
    float m  = s1 * (1.0f/128.0f);
    float sc = rsqrtf(s2 * (1.0f/128.0f) - m*m + 1e-5f);
    float o0 = 0.f, o1 = 0.f;
    #pragma unroll
    for (int d4 = 0; d4 < 8; d4++) {
      int d = q*32 + d4*4;
      float4 g4  = *(const float4*)&pfg[d];
      float4 b4  = *(const float4*)&pfb[d];
      float4 h0  = *(const float4*)&hw[d];
      float4 h14 = *(const float4*)&hw[128 + d];
      float x0 = (xv[d4].x - m)*sc*g4.x + b4.x;
      float x1 = (xv[d4].y - m)*sc*g4.y + b4.y;
      float x2 = (xv[d4].z - m)*sc*g4.z + b4.z;
      float x3 = (xv[d4].w - m)*sc*g4.w + b4.w;
      o0 = fmaf(x0,h0.x,  fmaf(x1,h0.y,  fmaf(x2,h0.z,  fmaf(x3,h0.w,  o0))));
      o1 = fmaf(x0,h14.x, fmaf(x1,h14.y, fmaf(x2,h14.z, fmaf(x3,h14.w, o1))));
    }
    o0 += __shfl_xor(o0, 1); o0 += __shfl_xor(o0, 2);
    o1 += __shfl_xor(o1, 1); o1 += __shfl_xor(o1, 2);
    if (q == 0) {
      int gi = ((wg*GE + e)*3 + w)*2;
      out[gi]     = o0 + hb[0];
      out[gi + 1] = o1 + hb[1];
    }
  }
}

// ---------------------------------------------------------------------------
extern "C" void kernel_launch(void* const* d_in, const int* in_sizes, int n_in,
                              void* d_out, int out_size, void* d_ws, size_t ws_size,
                              hipStream_t stream) {
  const float* tl       = (const float*)d_in[0];
  const float* tr       = (const float*)d_in[1];
  const float* coord_w  = (const float*)d_in[2];
  const float* coord_b  = (const float*)d_in[3];
  const float* pos_emb  = (const float*)d_in[4];
  const float* side_emb = (const float*)d_in[5];
  const float* query_emb= (const float*)d_in[6];
  const float* tln_g    = (const float*)d_in[7];
  const float* tln_b    = (const float*)d_in[8];
  const float* qln_g    = (const float*)d_in[9];
  const float* qln_b    = (const float*)d_in[10];
  const float* ipw      = (const float*)d_in[11];
  const float* ipb      = (const float*)d_in[12];
  const float* opw      = (const float*)d_in[13];
  const float* opb      = (const float*)d_in[14];
  const float* f1w      = (const float*)d_in[15];
  const float* f1b      = (const float*)d_in[16];
  const float* f2w      = (const float*)d_in[17];
  const float* f2b2     = (const float*)d_in[18];
  const float* pag      = (const float*)d_in[19];
  const float* pab      = (const float*)d_in[20];
  const float* pfg      = (const float*)d_in[21];
  const float* pfb      = (const float*)d_in[22];
  const float* hw       = (const float*)d_in[23];
  const float* hb       = (const float*)d_in[24];
  char* ws = (char*)d_ws;

  k_tables<<<21, 128, 0, stream>>>(coord_w, coord_b, pos_emb, side_emb, query_emb,
                                   tln_g, tln_b, qln_g, qln_b, ipw, ipb, ws);
  k_build<<<160, 256, 0, stream>>>(opw, opb, f1w, f2w, ws);
  k_main<<<32768 / GE, 256, 0, stream>>>(tl, tr, f1b, f2b2, pag, pab, pfg, pfb,
                                         hw, hb, ws, (float*)d_out);
}

// Round 2
// 188.340 us; speedup vs baseline: 1.1461x; 1.1461x over previous
//
#include <hip/hip_runtime.h>
#include <hip/hip_bf16.h>

// ---------------------------------------------------------------------------
// TransformerPlanner: algebra-collapsed fused implementation.
//
// R2 changes vs R1 (102us k_main, Occ 26%, everything idle => latency-bound):
//  - S1 (48x132 f32, 25 KB) ELIMINATED. LN after GEMM1 and the final
//    LN+head are computed from MFMA fragments in registers: shfl_xor
//    column reduce -> tiny Pp[48][4] cross-wave partials -> m,sc -> X/out.
//  - fc1/fc2 split into two K=128 halves sharing one 13 KB h1 buffer
//    (fc2 accumulators persist in registers across halves).
//  - LDS 50688 -> 32256 B  =>  4 WGs/CU (16 waves/CU) under
//    __launch_bounds__(256,4) (VGPR<=128).
// ---------------------------------------------------------------------------

typedef __bf16 bf16x8 __attribute__((ext_vector_type(8)));
typedef float  f32x4  __attribute__((ext_vector_type(4)));
static_assert(sizeof(bf16x8) == 16, "bf16x8 must be 16B");

__device__ __forceinline__ unsigned short f2b(float x) {
  __bf16 h = (__bf16)x;
  return __builtin_bit_cast(unsigned short, h);
}
__device__ __forceinline__ float b2f(unsigned short u) {
  return (float)__builtin_bit_cast(__bf16, u);
}
__device__ __forceinline__ float dot4(float4 a, float4 b) {
  return a.x*b.x + a.y*b.y + a.z*b.z + a.w*b.w;
}
__device__ __forceinline__ f32x4 mfma16(bf16x8 a, bf16x8 b, f32x4 c) {
  return __builtin_amdgcn_mfma_f32_16x16x32_bf16(a, b, c, 0, 0, 0);
}

// ---- workspace layout (byte offsets into d_ws) ----
#define WS_OM    0          // ushort[128*192]  combined attn GEMM weights (row n, K=192)
#define WS_FC1   49152      // ushort[256*128]  fc1 bf16 row-major (N,K)
#define WS_FC2   114688     // ushort[128*256]  fc2 bf16 row-major (N,K)
#define WS_VB    180224     // float[20*128]
#define WS_VU    190464     // float[128]
#define WS_VW    190976     // float[128]
#define WS_VC    191488     // float[128]
#define WS_QN    192000     // float[3*128]  LN'd queries
#define WS_SB    193536     // float[480]    Sb[w][h][t]
#define WS_SU    195456     // float[72]     Su[24],Sw[24],Sc[24]
#define WS_SCAL  195744     // float[3]      Suu,Sww,Suw
#define WS_SUB   195756     // float[20]
#define WS_SWB   195836     // float[20]
#define WS_SBB   195916     // float[20]

// ---------------------------------------------------------------------------
__device__ float mean128(float v, volatile float* red) {
  #pragma unroll
  for (int o = 32; o; o >>= 1) v += __shfl_down(v, o, 64);
  __syncthreads();
  if ((threadIdx.x & 63) == 0) red[threadIdx.x >> 6] = v;
  __syncthreads();
  return (red[0] + red[1]) * (1.0f / 128.0f);
}

__global__ void k_tables(
    const float* __restrict__ coord_w, const float* __restrict__ coord_b,
    const float* __restrict__ pos_emb, const float* __restrict__ side_emb,
    const float* __restrict__ query_emb,
    const float* __restrict__ tln_g, const float* __restrict__ tln_b,
    const float* __restrict__ qln_g, const float* __restrict__ qln_b,
    const float* __restrict__ ipw, const float* __restrict__ ipb,
    char* __restrict__ ws)
{
  __shared__ float red[2];
  __shared__ float qn[3][128];
  __shared__ float qmat[3][128];
  __shared__ float vecA[128];
  __shared__ float vecB[128];
  __shared__ float vecC[128];
  __shared__ float kuA[128];
  __shared__ float kwA[128];
  __shared__ float kcA[128];
  const int d = threadIdx.x;      // 128 threads
  const int t = blockIdx.x;       // 0..19 = token blocks, 20 = misc

  float u  = coord_w[d*2+0];
  float w2 = coord_w[d*2+1];
  float g  = tln_g[d];
  float mu = mean128(u,  red);
  float mw = mean128(w2, red);
  float uh = u - mu, wh = w2 - mw;

  // LN(query_emb)
  #pragma unroll
  for (int w = 0; w < 3; w++) {
    float qe = query_emb[w*128 + d];
    float m  = mean128(qe, red);
    float m2 = mean128(qe*qe, red);
    float var = m2 - m*m;
    qn[w][d] = (qe - m) * rsqrtf(var + 1e-5f) * qln_g[d] + qln_b[d];
  }
  __syncthreads();
  // q = qn @ wq^T + bq   (wq = ipw rows [0,128))
  {
    const float* wqr = ipw + d*128;
    float a0 = 0, a1 = 0, a2 = 0;
    for (int k4 = 0; k4 < 32; k4++) {
      float4 wv4 = *(const float4*)&wqr[k4*4];
      a0 += dot4(wv4, *(const float4*)&qn[0][k4*4]);
      a1 += dot4(wv4, *(const float4*)&qn[1][k4*4]);
      a2 += dot4(wv4, *(const float4*)&qn[2][k4*4]);
    }
    float bq = ipb[d];
    qmat[0][d] = a0 + bq; qmat[1][d] = a1 + bq; qmat[2][d] = a2 + bq;
  }
  __syncthreads();

  if (t < 20) {
    float base = coord_b[d] + pos_emb[(t % 10)*128 + d] + side_emb[(t < 10 ? 0 : 1)*128 + d];
    float mb = mean128(base, red);
    float bh = base - mb;
    float sub = mean128(uh*bh, red);
    float swb = mean128(wh*bh, red);
    float sbb = mean128(bh*bh, red);
    if (d == 0) {
      ((float*)(ws + WS_SUB))[t] = sub;
      ((float*)(ws + WS_SWB))[t] = swb;
      ((float*)(ws + WS_SBB))[t] = sbb;
    }
    vecA[d] = bh * g;
    __syncthreads();
    const float* wkr = ipw + (128 + d)*128;
    const float* wvr = ipw + (256 + d)*128;
    float kb = 0, vb = 0;
    for (int k4 = 0; k4 < 32; k4++) {
      float4 a4 = *(const float4*)&vecA[k4*4];
      kb += dot4(*(const float4*)&wkr[k4*4], a4);
      vb += dot4(*(const float4*)&wvr[k4*4], a4);
    }
    kuA[d] = kb;
    ((float*)(ws + WS_VB))[t*128 + d] = vb;
    __syncthreads();
    if (d < 24) {
      int w = d / 8, h = d % 8;
      float s = 0;
      #pragma unroll
      for (int dl = 0; dl < 16; dl++) s += qmat[w][h*16 + dl] * kuA[h*16 + dl];
      ((float*)(ws + WS_SB))[(w*8 + h)*20 + t] = 0.25f * s;
    }
  } else {
    float suu = mean128(uh*uh, red);
    float sww = mean128(wh*wh, red);
    float suw = mean128(uh*wh, red);
    if (d == 0) {
      float* sc = (float*)(ws + WS_SCAL);
      sc[0] = suu; sc[1] = sww; sc[2] = suw;
    }
    vecA[d] = uh * g; vecB[d] = wh * g; vecC[d] = tln_b[d];
    __syncthreads();
    const float* wkr = ipw + (128 + d)*128;
    const float* wvr = ipw + (256 + d)*128;
    float ku = 0, kw = 0, kc = 0, vu = 0, vw = 0, vc = 0;
    for (int k4 = 0; k4 < 32; k4++) {
      float4 a4 = *(const float4*)&vecA[k4*4];
      float4 b4 = *(const float4*)&vecB[k4*4];
      float4 c4 = *(const float4*)&vecC[k4*4];
      float4 kv = *(const float4*)&wkr[k4*4];
      float4 vv = *(const float4*)&wvr[k4*4];
      ku += dot4(kv, a4); kw += dot4(kv, b4); kc += dot4(kv, c4);
      vu += dot4(vv, a4); vw += dot4(vv, b4); vc += dot4(vv, c4);
    }
    kc += ipb[128 + d]; vc += ipb[256 + d];
    ((float*)(ws + WS_VU))[d] = vu;
    ((float*)(ws + WS_VW))[d] = vw;
    ((float*)(ws + WS_VC))[d] = vc;
    kuA[d] = ku; kwA[d] = kw; kcA[d] = kc;
    float* qnw = (float*)(ws + WS_QN);
    qnw[0*128 + d] = qn[0][d]; qnw[1*128 + d] = qn[1][d]; qnw[2*128 + d] = qn[2][d];
    __syncthreads();
    if (d < 24) {
      int w = d / 8, h = d % 8;
      float su = 0, sw = 0, sc2 = 0;
      #pragma unroll
      for (int dl = 0; dl < 16; dl++) {
        float q = qmat[w][h*16 + dl];
        su  += q * kuA[h*16 + dl];
        sw  += q * kwA[h*16 + dl];
        sc2 += q * kcA[h*16 + dl];
      }
      float* o = (float*)(ws + WS_SU);
      o[ 0 + w*8 + h] = 0.25f * su;
      o[24 + w*8 + h] = 0.25f * sw;
      o[48 + w*8 + h] = 0.25f * sc2;
    }
  }
}

// Build OM (128x192) and bf16 repack of fc1/fc2.
__global__ void k_build(
    const float* __restrict__ opw, const float* __restrict__ opb,
    const float* __restrict__ f1w, const float* __restrict__ f2w,
    char* __restrict__ ws)
{
  const int b = blockIdx.x, tid = threadIdx.x;
  if (b < 128) {
    __shared__ float Or[128];
    if (tid < 128) Or[tid] = opw[b*128 + tid];
    __syncthreads();
    if (tid < 192) {
      const float* VB = (const float*)(ws + WS_VB);
      const float* VU = (const float*)(ws + WS_VU);
      const float* VW = (const float*)(ws + WS_VW);
      const float* VC = (const float*)(ws + WS_VC);
      float val = 0.0f;
      if (tid < 160) {
        int h = tid / 20, tt = tid % 20;
        #pragma unroll
        for (int dl = 0; dl < 16; dl++) val += Or[h*16 + dl] * VB[tt*128 + h*16 + dl];
      } else if (tid < 168) {
        int h = tid - 160;
        #pragma unroll
        for (int dl = 0; dl < 16; dl++) val += Or[h*16 + dl] * VU[h*16 + dl];
      } else if (tid < 176) {
        int h = tid - 168;
        #pragma unroll
        for (int dl = 0; dl < 16; dl++) val += Or[h*16 + dl] * VW[h*16 + dl];
      } else if (tid == 176) {
        for (int d = 0; d < 128; d++) val += Or[d] * VC[d];
        val += opb[b];
      } else {
        val = 0.0f;
      }
      ((unsigned short*)(ws + WS_OM))[b*192 + tid] = f2b(val);
    }
  } else if (b < 144) {
    unsigned short* dst = (unsigned short*)(ws + WS_FC1);
    int i0 = (b - 128)*2048;
    #pragma unroll
    for (int j = 0; j < 8; j++) { int i = i0 + j*256 + tid; dst[i] = f2b(f1w[i]); }
  } else {
    unsigned short* dst = (unsigned short*)(ws + WS_FC2);
    int i0 = (b - 144)*2048;
    #pragma unroll
    for (int j = 0; j < 8; j++) { int i = i0 + j*256 + tid; dst[i] = f2b(f2w[i]); }
  }
}

// ---------------------------------------------------------------------------
// Main fused kernel: 16 batch elements per WG (M = 48 rows), 256 threads.
// LDS 32256 B -> 4 WGs/CU (VGPR-capped at 128 via __launch_bounds__(256,4)).
//
// LDS regions / liveness:
//  A [0,19200)     : Z 48x200 bf16 (P0-P3 reads) ; X 48x136 bf16 aliases [0,13056)
//                    after all Z reads complete (post b4); [13056,16512) hosts
//                    Pp2/msc2/Op for the P6b fragment-LN epilogue.
//  B [19200,32256) : P0-P3: xr/yr/rsA/Sbl/Sul/QN/pag/pab/Pp/msc staging;
//                    P5/P6: h1 half-buffer 48x136 bf16 (both K-halves).
#define GE 16
#define MR 48
#define SMEM_SZ 32256

__global__ __launch_bounds__(256, 4) void k_main(
    const float* __restrict__ tl, const float* __restrict__ tr,
    const float* __restrict__ f1b, const float* __restrict__ f2b_,
    const float* __restrict__ pag, const float* __restrict__ pab,
    const float* __restrict__ pfg, const float* __restrict__ pfb,
    const float* __restrict__ hw, const float* __restrict__ hb,
    const char* __restrict__ ws, float* __restrict__ out)
{
  __shared__ __align__(16) char smem[SMEM_SZ];
  // region A
  unsigned short* Z  = (unsigned short*)(smem);          // 48x200 (P0-P3)
  unsigned short* X  = (unsigned short*)(smem);          // 48x136 (aliases Z, post-P3)
  float* Pp2  = (float*)(smem + 13056);                  // [48][4] float2
  float* msc2 = (float*)(smem + 14592);                  // [48] float2
  float* Op   = (float*)(smem + 14976);                  // [48][4] float2
  // region B
  float* xr   = (float*)(smem + 19200);                  // 16x20
  float* yr   = (float*)(smem + 20480);
  float* rsA  = (float*)(smem + 21760);
  float* Sbl  = (float*)(smem + 23040);                  // 480
  float* SulA = (float*)(smem + 24960);                  // 72 (Su,Sw,Sc)
  float* QNl  = (float*)(smem + 25248);                  // 3x128
  float* pagl = (float*)(smem + 26784);                  // 128
  float* pabl = (float*)(smem + 27296);                  // 128
  float* Pp   = (float*)(smem + 27808);                  // [48][4] float2
  float* mscA = (float*)(smem + 29344);                  // [48] float2
  unsigned short* h1 = (unsigned short*)(smem + 19200);  // 48x136 (P5/P6)

  const unsigned short* OM = (const unsigned short*)(ws + WS_OM);
  const unsigned short* W1 = (const unsigned short*)(ws + WS_FC1);
  const unsigned short* W2 = (const unsigned short*)(ws + WS_FC2);
  const float* QNw  = (const float*)(ws + WS_QN);
  const float* SBw  = (const float*)(ws + WS_SB);
  const float* SUw  = (const float*)(ws + WS_SU);
  const float* SCAL = (const float*)(ws + WS_SCAL);
  const float* SUB  = (const float*)(ws + WS_SUB);
  const float* SWB  = (const float*)(ws + WS_SWB);
  const float* SBB  = (const float*)(ws + WS_SBB);

  const int tid  = threadIdx.x;
  const int wg   = blockIdx.x;
  const int lane = tid & 63;
  const int wv   = tid >> 6;
  const int c    = lane & 15;     // MFMA column-in-tile / A-row index
  const int g    = lane >> 4;     // MFMA k-slice / output row-group
  const int nb   = wv * 32;       // N-slice base for this wave

  // ---- P0: stage tables, init Z constant tail, load coords ----
  for (int i = tid; i < 480; i += 256) Sbl[i] = SBw[i];
  if (tid < 72) SulA[tid] = SUw[tid];
  for (int i = tid; i < 384; i += 256) QNl[i] = QNw[i];
  if (tid < 128) { pagl[tid] = pag[tid]; pabl[tid] = pab[tid]; }
  if (tid < 48) {
    unsigned short* Zr = Z + tid*200;
    Zr[176] = 0x3F80;                  // bf16 1.0
    #pragma unroll
    for (int i = 177; i < 192; i++) Zr[i] = 0;
  }
  if (tid < 160) {
    int half = tid / 80;               // 0 = left, 1 = right
    int i4   = tid % 80;
    const float* src = half ? tr : tl;
    float4 v = *(const float4*)(src + wg*(GE*20) + i4*4);
    int e  = i4 / 5;
    int j  = (i4 % 5) * 4;
    int t0 = half*10 + j/2;
    xr[e*20 + t0]     = v.x; yr[e*20 + t0]     = v.y;
    xr[e*20 + t0 + 1] = v.z; yr[e*20 + t0 + 1] = v.w;
  }
  __syncthreads();                                        // b1

  // ---- P1: rs_t = rsqrt(quadratic(x,y) + eps); xr,yr <- x*rs, y*rs ----
  {
    float suu = SCAL[0], sww = SCAL[1], suw = SCAL[2];
    for (int i = tid; i < GE*20; i += 256) {
      int t = i % 20;
      float x = xr[i], y = yr[i];
      float var = suu*x*x + sww*y*y + 2.0f*suw*x*y
                + 2.0f*SUB[t]*x + 2.0f*SWB[t]*y + SBB[t];
      float rv = rsqrtf(var + 1e-5f);
      rsA[i] = rv; xr[i] = x*rv; yr[i] = y*rv;
    }
  }
  __syncthreads();                                        // b2

  // ---- P2: scores + softmax + P,Q -> Z rows (bf16) ----
  if (tid < 128) {
    int e = tid >> 3, h = tid & 7;
    float xa[20], ya[20], ra[20];
    #pragma unroll
    for (int tb = 0; tb < 5; tb++) {
      float4 xv = *(const float4*)&xr[e*20 + tb*4];
      float4 yv = *(const float4*)&yr[e*20 + tb*4];
      float4 rv = *(const float4*)&rsA[e*20 + tb*4];
      xa[tb*4+0]=xv.x; xa[tb*4+1]=xv.y; xa[tb*4+2]=xv.z; xa[tb*4+3]=xv.w;
      ya[tb*4+0]=yv.x; ya[tb*4+1]=yv.y; ya[tb*4+2]=yv.z; ya[tb*4+3]=yv.w;
      ra[tb*4+0]=rv.x; ra[tb*4+1]=rv.y; ra[tb*4+2]=rv.z; ra[tb*4+3]=rv.w;
    }
    float s[3][20];
    #pragma unroll
    for (int w = 0; w < 3; w++) {
      float suv = SulA[w*8 + h], swv = SulA[24 + w*8 + h], scv = SulA[48 + w*8 + h];
      const float* sb = &Sbl[(w*8 + h)*20];
      #pragma unroll
      for (int tb = 0; tb < 5; tb++) {
        float4 s4 = *(const float4*)&sb[tb*4];
        s[w][tb*4+0] = fmaf(xa[tb*4+0],suv, fmaf(ya[tb*4+0],swv, fmaf(ra[tb*4+0],s4.x, scv)));
        s[w][tb*4+1] = fmaf(xa[tb*4+1],suv, fmaf(ya[tb*4+1],swv, fmaf(ra[tb*4+1],s4.y, scv)));
        s[w][tb*4+2] = fmaf(xa[tb*4+2],suv, fmaf(ya[tb*4+2],swv, fmaf(ra[tb*4+2],s4.z, scv)));
        s[w][tb*4+3] = fmaf(xa[tb*4+3],suv, fmaf(ya[tb*4+3],swv, fmaf(ra[tb*4+3],s4.w, scv)));
      }
    }
    unsigned short* Zr0 = Z + e*3*200;
    #pragma unroll
    for (int w = 0; w < 3; w++) {
      float m = s[w][0];
      #pragma unroll
      for (int t2 = 1; t2 < 20; t2++) m = fmaxf(m, s[w][t2]);
      float sum = 0;
      #pragma unroll
      for (int t2 = 0; t2 < 20; t2++) { float p = __expf(s[w][t2] - m); s[w][t2] = p; sum += p; }
      float inv = 1.0f / sum;
      float P = 0, Q = 0;
      #pragma unroll
      for (int t2 = 0; t2 < 20; t2++) { P = fmaf(s[w][t2], xa[t2], P); Q = fmaf(s[w][t2], ya[t2], Q); }
      P *= inv; Q *= inv;
      unsigned short* Zr = Zr0 + w*200;
      #pragma unroll
      for (int t2 = 0; t2 < 10; t2++) {
        unsigned int lo = f2b(s[w][2*t2]   * ra[2*t2]   * inv);
        unsigned int hi = f2b(s[w][2*t2+1] * ra[2*t2+1] * inv);
        *(unsigned int*)&Zr[h*20 + 2*t2] = lo | (hi << 16);
      }
      Zr[160 + h] = f2b(P);
      Zr[168 + h] = f2b(Q);
    }
  }
  __syncthreads();                                        // b3

  // ---- P3: GEMM1 attn_out = Z(48x192) @ OM^T, fused LN -> X bf16 ----
  {
    bf16x8 Bf[2][6];
    #pragma unroll
    for (int nt = 0; nt < 2; nt++)
      #pragma unroll
      for (int kt = 0; kt < 6; kt++)
        Bf[nt][kt] = *(const bf16x8*)(OM + (nb + nt*16 + c)*192 + kt*32 + g*8);
    f32x4 acc[3][2];
    #pragma unroll
    for (int mt = 0; mt < 3; mt++)
      #pragma unroll
      for (int nt = 0; nt < 2; nt++) acc[mt][nt] = (f32x4){0.f,0.f,0.f,0.f};
    #pragma unroll
    for (int kt = 0; kt < 6; kt++) {
      bf16x8 Af[3];
      #pragma unroll
      for (int mt = 0; mt < 3; mt++)
        Af[mt] = *(const bf16x8*)(Z + (mt*16 + c)*200 + kt*32 + g*8);
      #pragma unroll
      for (int mt = 0; mt < 3; mt++)
        #pragma unroll
        for (int nt = 0; nt < 2; nt++)
          acc[mt][nt] = mfma16(Af[mt], Bf[nt][kt], acc[mt][nt]);
    }
    // fragment-LN: add queries_n, column-group reduce for mean/var
    float p1[3][4], p2[3][4];
    #pragma unroll
    for (int mt = 0; mt < 3; mt++)
      #pragma unroll
      for (int j = 0; j < 4; j++) {
        int row = mt*16 + g*4 + j;
        int w = row % 3;
        float v0 = acc[mt][0][j] + QNl[w*128 + nb + c];
        float v1 = acc[mt][1][j] + QNl[w*128 + nb + 16 + c];
        acc[mt][0][j] = v0; acc[mt][1][j] = v1;
        p1[mt][j] = v0 + v1;
        p2[mt][j] = v0*v0 + v1*v1;
      }
    #pragma unroll
    for (int mt = 0; mt < 3; mt++)
      #pragma unroll
      for (int j = 0; j < 4; j++) {
        #pragma unroll
        for (int mk = 1; mk <= 8; mk <<= 1) {
          p1[mt][j] += __shfl_xor(p1[mt][j], mk, 64);
          p2[mt][j] += __shfl_xor(p2[mt][j], mk, 64);
        }
      }
    if (c < 4) {
      #pragma unroll
      for (int mt = 0; mt < 3; mt++) {
        float a = (c==0)?p1[mt][0]:(c==1)?p1[mt][1]:(c==2)?p1[mt][2]:p1[mt][3];
        float b = (c==0)?p2[mt][0]:(c==1)?p2[mt][1]:(c==2)?p2[mt][2]:p2[mt][3];
        int row = mt*16 + g*4 + c;
        *(float2*)&Pp[row*8 + wv*2] = make_float2(a, b);
      }
    }
    __syncthreads();                                      // b4 (also: all Z reads done)
    if (tid < 192) {
      int row = tid >> 2, q = tid & 3;
      float2 pp = *(const float2*)&Pp[row*8 + q*2];
      float s1v = pp.x, s2v = pp.y;
      s1v += __shfl_xor(s1v, 1, 64); s1v += __shfl_xor(s1v, 2, 64);
      s2v += __shfl_xor(s2v, 1, 64); s2v += __shfl_xor(s2v, 2, 64);
      if (q == 0) {
        float m = s1v * (1.0f/128.0f);
        float var = s2v * (1.0f/128.0f) - m*m;
        *(float2*)&mscA[row*2] = make_float2(m, rsqrtf(var + 1e-5f));
      }
    }
    __syncthreads();                                      // b5
    // X = LN'd x, written straight from fragments (X aliases dead Z)
    {
      float pg0 = pagl[nb + c],      pb0 = pabl[nb + c];
      float pg1 = pagl[nb + 16 + c], pb1 = pabl[nb + 16 + c];
      #pragma unroll
      for (int mt = 0; mt < 3; mt++)
        #pragma unroll
        for (int j = 0; j < 4; j++) {
          int row = mt*16 + g*4 + j;
          float2 ms = *(const float2*)&mscA[row*2];
          X[row*136 + nb + c]      = f2b((acc[mt][0][j] - ms.x)*ms.y*pg0 + pb0);
          X[row*136 + nb + 16 + c] = f2b((acc[mt][1][j] - ms.x)*ms.y*pg1 + pb1);
        }
    }
  }
  __syncthreads();                                        // b6

  // ---- P5/P6: FFN in two K=128 halves sharing h1 (48x136 bf16) ----
  f32x4 acc2[3][2];
  #pragma unroll
  for (int mt = 0; mt < 3; mt++)
    #pragma unroll
    for (int nt = 0; nt < 2; nt++) acc2[mt][nt] = (f32x4){0.f,0.f,0.f,0.f};

  #pragma unroll
  for (int h = 0; h < 2; h++) {
    // P5: fc1 half -> relu -> h1
    {
      bf16x8 Bf[2][4];
      #pragma unroll
      for (int nt = 0; nt < 2; nt++)
        #pragma unroll
        for (int kt = 0; kt < 4; kt++)
          Bf[nt][kt] = *(const bf16x8*)(W1 + (h*128 + nb + nt*16 + c)*128 + kt*32 + g*8);
      f32x4 acc[3][2];
      #pragma unroll
      for (int mt = 0; mt < 3; mt++)
        #pragma unroll
        for (int nt = 0; nt < 2; nt++) acc[mt][nt] = (f32x4){0.f,0.f,0.f,0.f};
      #pragma unroll
      for (int kt = 0; kt < 4; kt++) {
        bf16x8 Af[3];
        #pragma unroll
        for (int mt = 0; mt < 3; mt++)
          Af[mt] = *(const bf16x8*)(X + (mt*16 + c)*136 + kt*32 + g*8);
        #pragma unroll
        for (int mt = 0; mt < 3; mt++)
          #pragma unroll
          for (int nt = 0; nt < 2; nt++)
            acc[mt][nt] = mfma16(Af[mt], Bf[nt][kt], acc[mt][nt]);
      }
      float bb0 = f1b[h*128 + nb + c];
      float bb1 = f1b[h*128 + nb + 16 + c];
      #pragma unroll
      for (int mt = 0; mt < 3; mt++)
        #pragma unroll
        for (int j = 0; j < 4; j++) {
          int row = mt*16 + g*4 + j;
          h1[row*136 + nb + c]      = f2b(fmaxf(acc[mt][0][j] + bb0, 0.0f));
          h1[row*136 + nb + 16 + c] = f2b(fmaxf(acc[mt][1][j] + bb1, 0.0f));
        }
    }
    __syncthreads();                                      // b7 / b9
    // P6: fc2 partial over this K-half, accumulate into acc2
    {
      bf16x8 Bf[2][4];
      #pragma unroll
      for (int nt = 0; nt < 2; nt++)
        #pragma unroll
        for (int kt = 0; kt < 4; kt++)
          Bf[nt][kt] = *(const bf16x8*)(W2 + (nb + nt*16 + c)*256 + h*128 + kt*32 + g*8);
      #pragma unroll
      for (int kt = 0; kt < 4; kt++) {
        bf16x8 Af[3];
        #pragma unroll
        for (int mt = 0; mt < 3; mt++)
          Af[mt] = *(const bf16x8*)(h1 + (mt*16 + c)*136 + kt*32 + g*8);
        #pragma unroll
        for (int mt = 0; mt < 3; mt++)
          #pragma unroll
          for (int nt = 0; nt < 2; nt++)
            acc2[mt][nt] = mfma16(Af[mt], Bf[nt][kt], acc2[mt][nt]);
      }
    }
    if (h == 0) __syncthreads();                          // b8 (h1 rewrite guard)
  }

  // ---- P6b epilogue: h2+bias+residual -> fragment-LN -> head -> out ----
  {
    float bb0 = f2b_[nb + c];
    float bb1 = f2b_[nb + 16 + c];
    float p1[3][4], p2[3][4];
    #pragma unroll
    for (int mt = 0; mt < 3; mt++)
      #pragma unroll
      for (int j = 0; j < 4; j++) {
        int row = mt*16 + g*4 + j;
        float v0 = acc2[mt][0][j] + bb0 + b2f(X[row*136 + nb + c]);
        float v1 = acc2[mt][1][j] + bb1 + b2f(X[row*136 + nb + 16 + c]);
        acc2[mt][0][j] = v0; acc2[mt][1][j] = v1;
        p1[mt][j] = v0 + v1;
        p2[mt][j] = v0*v0 + v1*v1;
      }
    #pragma unroll
    for (int mt = 0; mt < 3; mt++)
      #pragma unroll
      for (int j = 0; j < 4; j++) {
        #pragma unroll
        for (int mk = 1; mk <= 8; mk <<= 1) {
          p1[mt][j] += __shfl_xor(p1[mt][j], mk, 64);
          p2[mt][j] += __shfl_xor(p2[mt][j], mk, 64);
        }
      }
    if (c < 4) {
      #pragma unroll
      for (int mt = 0; mt < 3; mt++) {
        float a = (c==0)?p1[mt][0]:(c==1)?p1[mt][1]:(c==2)?p1[mt][2]:p1[mt][3];
        float b = (c==0)?p2[mt][0]:(c==1)?p2[mt][1]:(c==2)?p2[mt][2]:p2[mt][3];
        int row = mt*16 + g*4 + c;
        *(float2*)&Pp2[row*8 + wv*2] = make_float2(a, b);
      }
    }
    __syncthreads();                                      // b10
    if (tid < 192) {
      int row = tid >> 2, q = tid & 3;
      float2 pp = *(const float2*)&Pp2[row*8 + q*2];
      float s1v = pp.x, s2v = pp.y;
      s1v += __shfl_xor(s1v, 1, 64); s1v += __shfl_xor(s1v, 2, 64);
      s2v += __shfl_xor(s2v, 1, 64); s2v += __shfl_xor(s2v, 2, 64);
      if (q == 0) {
        float m = s1v * (1.0f/128.0f);
        float var = s2v * (1.0f/128.0f) - m*m;
        *(float2*)&msc2[row*2] = make_float2(m, rsqrtf(var + 1e-5f));
      }
    }
    __syncthreads();                                      // b11
    {
      float fg0 = pfg[nb + c],        fb0 = pfb[nb + c];
      float fg1 = pfg[nb + 16 + c],   fb1 = pfb[nb + 16 + c];
      float hw00 = hw[nb + c],        hw01 = hw[nb + 16 + c];
      float hw10 = hw[128 + nb + c],  hw11 = hw[128 + nb + 16 + c];
      float o0[3][4], o1[3][4];
      #pragma unroll
      for (int mt = 0; mt < 3; mt++)
        #pragma unroll
        for (int j = 0; j < 4; j++) {
          int row = mt*16 + g*4 + j;
          float2 ms = *(const float2*)&msc2[row*2];
          float x0 = (acc2[mt][0][j] - ms.x)*ms.y*fg0 + fb0;
          float x1 = (acc2[mt][1][j] - ms.x)*ms.y*fg1 + fb1;
          o0[mt][j] = x0*hw00 + x1*hw01;
          o1[mt][j] = x0*hw10 + x1*hw11;
        }
      #pragma unroll
      for (int mt = 0; mt < 3; mt++)
        #pragma unroll
        for (int j = 0; j < 4; j++) {
          #pragma unroll
          for (int mk = 1; mk <= 8; mk <<= 1) {
            o0[mt][j] += __shfl_xor(o0[mt][j], mk, 64);
            o1[mt][j] += __shfl_xor(o1[mt][j], mk, 64);
          }
        }
      if (c < 4) {
        #pragma unroll
        for (int mt = 0; mt < 3; mt++) {
          float a = (c==0)?o0[mt][0]:(c==1)?o0[mt][1]:(c==2)?o0[mt][2]:o0[mt][3];
          float b = (c==0)?o1[mt][0]:(c==1)?o1[mt][1]:(c==2)?o1[mt][2]:o1[mt][3];
          int row = mt*16 + g*4 + c;
          *(float2*)&Op[row*8 + wv*2] = make_float2(a, b);
        }
      }
    }
    __syncthreads();                                      // b12
    if (tid < 48) {
      float4 a = *(const float4*)&Op[tid*8];
      float4 b = *(const float4*)&Op[tid*8 + 4];
      out[(wg*48 + tid)*2]     = a.x + a.z + b.x + b.z + hb[0];
      out[(wg*48 + tid)*2 + 1] = a.y + a.w + b.y + b.w + hb[1];
    }
  }
}

// ---------------------------------------------------------------------------
extern "C" void kernel_launch(void* const* d_in, const int* in_sizes, int n_in,
                              void* d_out, int out_size, void* d_ws, size_t ws_size,
                              hipStream_t stream) {
  const float* tl       = (const float*)d_in[0];
  const float* tr       = (const float*)d_in[1];
  const float* coord_w  = (const float*)d_in[2];
  const float* coord_b  = (const float*)d_in[3];
  const float* pos_emb  = (const float*)d_in[4];
  const float* side_emb = (const float*)d_in[5];
  const float* query_emb= (const float*)d_in[6];
  const float* tln_g    = (const float*)d_in[7];
  const float* tln_b    = (const float*)d_in[8];
  const float* qln_g    = (const float*)d_in[9];
  const float* qln_b    = (const float*)d_in[10];
  const float* ipw      = (const float*)d_in[11];
  const float* ipb      = (const float*)d_in[12];
  const float* opw      = (const float*)d_in[13];
  const float* opb      = (const float*)d_in[14];
  const float* f1w      = (const float*)d_in[15];
  const float* f1b      = (const float*)d_in[16];
  const float* f2w      = (const float*)d_in[17];
  const float* f2b2     = (const float*)d_in[18];
  const float* pag      = (const float*)d_in[19];
  const float* pab      = (const float*)d_in[20];
  const float* pfg      = (const float*)d_in[21];
  const float* pfb      = (const float*)d_in[22];
  const float* hw       = (const float*)d_in[23];
  const float* hb       = (const float*)d_in[24];
  char* ws = (char*)d_ws;

  k_tables<<<21, 128, 0, stream>>>(coord_w, coord_b, pos_emb, side_emb, query_emb,
                                   tln_g, tln_b, qln_g, qln_b, ipw, ipb, ws);
  k_build<<<160, 256, 0, stream>>>(opw, opb, f1w, f2w, ws);
  k_main<<<32768 / GE, 256, 0, stream>>>(tl, tr, f1b, f2b2, pag, pab, pfg, pfb,
                                         hw, hb, ws, (float*)d_out);
}